// Round 8
// baseline (1690.072 us; speedup 1.0000x reference)
//
#include <hip/hip_runtime.h>
#include <hip/hip_bf16.h>

#define DEV __device__ __forceinline__

typedef __attribute__((ext_vector_type(8))) short short8;
typedef __attribute__((ext_vector_type(4))) float f32x4;

DEV unsigned short f2bf(float f){
  unsigned int u = __builtin_bit_cast(unsigned int, f);
  u += 0x7FFFu + ((u >> 16) & 1u);
  return (unsigned short)(u >> 16);
}

DEV void gld_lds16(const void* g, void* l){
  __builtin_amdgcn_global_load_lds((const __attribute__((address_space(1))) void*)g,
                                   (__attribute__((address_space(3))) void*)l, 16, 0, 0);
}

// ---------------- embedding: h = wte[x] + pos ----------------
__global__ void k_embed(const int* __restrict__ x, const float* __restrict__ wte,
                        const float* __restrict__ pos, float* __restrict__ h){
  int i = blockIdx.x * 256 + threadIdx.x;           // total 8192*768
  int row = i / 768, d = i - row * 768;
  int s = row & 1023;
  h[i] = wte[x[row] * 768 + d] + pos[s * 768 + d];
}

// ---------------- layernorm (f32 in) -> bf16 out ----------------
__global__ void k_ln(const float* __restrict__ src, const float* __restrict__ g,
                     const float* __restrict__ b, unsigned short* __restrict__ out){
  int row = blockIdx.x, t = threadIdx.x;
  const float* p = src + (size_t)row * 768;
  float v0 = p[t], v1 = p[t + 256], v2 = p[t + 512];
  float s = v0 + v1 + v2;
  float sq = v0 * v0 + v1 * v1 + v2 * v2;
  #pragma unroll
  for(int m = 32; m >= 1; m >>= 1){ s += __shfl_xor(s, m); sq += __shfl_xor(sq, m); }
  __shared__ float red[8];
  int w = t >> 6;
  if((t & 63) == 0){ red[w] = s; red[4 + w] = sq; }
  __syncthreads();
  float S  = red[0] + red[1] + red[2] + red[3];
  float SQ = red[4] + red[5] + red[6] + red[7];
  float mu  = S * (1.0f / 768.0f);
  float var = SQ * (1.0f / 768.0f) - mu * mu;
  float inv = rsqrtf(var + 1e-5f);
  unsigned short* o = out + (size_t)row * 768;
  o[t]       = f2bf((v0 - mu) * inv * g[t]       + b[t]);
  o[t + 256] = f2bf((v1 - mu) * inv * g[t + 256] + b[t + 256]);
  o[t + 512] = f2bf((v2 - mu) * inv * g[t + 512] + b[t + 512]);
}

// ------- tiled transpose f32 src[R][C] -> bf16 dst[C][R], 128x32 tiles, 8B stores -------
// load: thread t reads 64B contiguous (16 f32) of row t>>1; store: 32 lanes x 8B = 256B
// contiguous per output row.
DEV void tr_tile128(float (*tl)[33], const float* __restrict__ src, unsigned short* __restrict__ dst,
                    int R, int C, int tx, int ty, int tid){
  int r0 = ty * 128, c0 = tx * 32;
  int lr = tid >> 1, lc = (tid & 1) * 16;
  const float* sp = src + (size_t)(r0 + lr) * C + c0 + lc;
  #pragma unroll
  for(int e = 0; e < 16; e++) tl[lr][lc + e] = sp[e];
  __syncthreads();
  int lx = tid & 31, ly = tid >> 5;                 // 32 x 8
  #pragma unroll
  for(int j = 0; j < 4; j++){
    int oc = ly + 8 * j;
    unsigned long long pk =
        (unsigned long long)f2bf(tl[4 * lx][oc]) |
        ((unsigned long long)f2bf(tl[4 * lx + 1][oc]) << 16) |
        ((unsigned long long)f2bf(tl[4 * lx + 2][oc]) << 32) |
        ((unsigned long long)f2bf(tl[4 * lx + 3][oc]) << 48);
    *(unsigned long long*)(dst + (size_t)(c0 + oc) * R + r0 + 4 * lx) = pk;
  }
}

// all-layer (or single-layer fallback) weight conversion:
// wq/wk/wv -> wqkv_t[2304][768] bf16, w1 -> w1_t[3072][768], w2 -> w2_t[768][3072],
// qkv bias packed [2304]. blockIdx.y = layer - l0, writes slot blockIdx.y.
// sections (128x32 tiles): qkv 3*(6*24)=432 | w1 6*96=576 | w2 24*24=576 | bias 1 -> 1585
__global__ void k_convert_all(const float* __restrict__ wq, const float* __restrict__ wk,
                              const float* __restrict__ wv, const float* __restrict__ w1,
                              const float* __restrict__ w2, const float* __restrict__ bq,
                              const float* __restrict__ bk, const float* __restrict__ bv,
                              unsigned short* __restrict__ wall, float* __restrict__ qkvb,
                              int l0){
  __shared__ float tl[128][33];
  int l = l0 + blockIdx.y, slot = blockIdx.y;
  int bid = blockIdx.x, tid = threadIdx.x;
  unsigned short* wqkv_t = wall + (size_t)slot * 6488064;
  unsigned short* w1_t   = wqkv_t + 1769472;
  unsigned short* w2_t   = w1_t + 2359296;
  float* qb = qkvb + slot * 2304;
  const float* wq_l = wq + (size_t)l * 589824;
  const float* wk_l = wk + (size_t)l * 589824;
  const float* wv_l = wv + (size_t)l * 589824;
  const float* w1_l = w1 + (size_t)l * 2359296;
  const float* w2_l = w2 + (size_t)l * 2359296;
  if(bid < 432){
    int which = bid / 144, t = bid - which * 144;   // 6 ty x 24 tx tiles of 768x768
    const float* src = which == 0 ? wq_l : which == 1 ? wk_l : wv_l;
    tr_tile128(tl, src, wqkv_t + (size_t)which * 589824, 768, 768, t % 24, t / 24, tid);
  } else if(bid < 432 + 576){
    int t = bid - 432;                              // 6 ty x 96 tx tiles of 768x3072
    tr_tile128(tl, w1_l, w1_t, 768, 3072, t % 96, t / 96, tid);
  } else if(bid < 432 + 1152){
    int t = bid - 1008;                             // 24 ty x 24 tx tiles of 3072x768
    tr_tile128(tl, w2_l, w2_t, 3072, 768, t % 24, t / 24, tid);
  } else {
    for(int i = tid; i < 768; i += 256){
      qb[i] = bq[l * 768 + i]; qb[768 + i] = bk[l * 768 + i]; qb[1536 + i] = bv[l * 768 + i];
    }
  }
}

__global__ void k_transpose(const float* __restrict__ src, unsigned short* __restrict__ dst,
                            int R, int C){
  __shared__ float tl[128][33];
  int nx = C / 32;
  tr_tile128(tl, src, dst, R, C, blockIdx.x % nx, blockIdx.x / nx, threadIdx.x);
}

// ---------------- bf16 GEMM: C[M,N] = A[M,K] * Bt[N,K]^T  (+ fused epilogue) ----------------
// 2-phase double-buffered m97 loop: per K-step issue next tile's global_load_lds FIRST,
// then compute current buffer, then one __syncthreads (drain waits on loads that flew
// during compute). Tile BM = MW*64 x BN = NB*32, MW*2 waves. T2 pre-swizzled source,
// T1 XCD-chunked block swizzle (requires nwg%8==0).
// MW=2 NB=4: 128x128, LDS 64KB dbuf, 2 blocks/CU. MW=2 NB=2: 128x64, 48KB, 3 blocks/CU.
// EPI 0: +bias, split q/k/v [B*H,S,64] bf16 | 1: +bias fast-GELU bf16 | 2: +bias h+= | 3: f32 out
template<int EPI, int MW, int NB>
__global__ __launch_bounds__(MW * 128, 4)
void k_gemm(const unsigned short* __restrict__ A, const unsigned short* __restrict__ Bt,
            const float* __restrict__ bias, int K,
            float* __restrict__ fout, unsigned short* __restrict__ o0,
            unsigned short* __restrict__ o1, unsigned short* __restrict__ o2){
  constexpr int THREADS = MW * 128;
  constexpr int AL = 4;                 // A gld_lds per thread
  constexpr int BL = (2 * NB) / MW;     // B gld_lds per thread
  __shared__ unsigned short As[2][MW * 64 * 64];
  __shared__ unsigned short Bs[2][NB * 32 * 64];
  int tid = threadIdx.x, w = tid >> 6, lane = tid & 63;
  int l15 = lane & 15, l4 = lane >> 4;
  int nbx = gridDim.x;
  int bid = blockIdx.y * nbx + blockIdx.x;
  int cpx = (nbx * gridDim.y) >> 3;
  int sid = (bid & 7) * cpx + (bid >> 3);       // XCD k owns sids [k*cpx,(k+1)*cpx)
  int bm = sid / nbx, bn = sid - bm * nbx;      // bm-major within chunk -> A-panel/XCD locality
  int N = nbx * NB * 32;
  int wr = w >> 1, wc = w & 1;
  f32x4 acc[4][NB] = {};
  int rowA[AL], colA[AL], rowB[BL], colB[BL];
  #pragma unroll
  for(int i = 0; i < AL; i++){
    int o = i * THREADS * 16 + tid * 16;
    int r = o >> 7, ch = (o >> 4) & 7;
    rowA[i] = r; colA[i] = ((ch ^ (r & 7)) << 3);
  }
  #pragma unroll
  for(int i = 0; i < BL; i++){
    int o = i * THREADS * 16 + tid * 16;
    int r = o >> 7, ch = (o >> 4) & 7;
    rowB[i] = r; colB[i] = ((ch ^ (r & 7)) << 3);
  }
  const size_t aBase = (size_t)bm * (MW * 64);
  const size_t bBase = (size_t)bn * (NB * 32);
  // prologue: stage k-step 0 into buffer 0
  #pragma unroll
  for(int i = 0; i < AL; i++)
    gld_lds16(A + (aBase + rowA[i]) * K + colA[i], (char*)As[0] + i * THREADS * 16 + tid * 16);
  #pragma unroll
  for(int i = 0; i < BL; i++)
    gld_lds16(Bt + (bBase + rowB[i]) * K + colB[i], (char*)Bs[0] + i * THREADS * 16 + tid * 16);
  __syncthreads();
  int cur = 0;
  for(int kt = 0; kt < K; kt += 64, cur ^= 1){
    if(kt + 64 < K){
      int kn = kt + 64;
      #pragma unroll
      for(int i = 0; i < AL; i++)
        gld_lds16(A + (aBase + rowA[i]) * K + kn + colA[i],
                  (char*)As[cur ^ 1] + i * THREADS * 16 + tid * 16);
      #pragma unroll
      for(int i = 0; i < BL; i++)
        gld_lds16(Bt + (bBase + rowB[i]) * K + kn + colB[i],
                  (char*)Bs[cur ^ 1] + i * THREADS * 16 + tid * 16);
    }
    const unsigned short* Ac = As[cur];
    const unsigned short* Bc = Bs[cur];
    #pragma unroll
    for(int s = 0; s < 2; s++){
      short8 af[4], bfr[NB];
      #pragma unroll
      for(int m = 0; m < 4; m++){
        int r = wr * 64 + m * 16 + l15;
        int ch = s * 4 + l4;
        af[m] = *(const short8*)(Ac + r * 64 + ((ch ^ (r & 7)) << 3));
      }
      #pragma unroll
      for(int n = 0; n < NB; n++){
        int r = wc * (NB * 16) + n * 16 + l15;
        int ch = s * 4 + l4;
        bfr[n] = *(const short8*)(Bc + r * 64 + ((ch ^ (r & 7)) << 3));
      }
      #pragma unroll
      for(int m = 0; m < 4; m++)
        #pragma unroll
        for(int n = 0; n < NB; n++)
          acc[m][n] = __builtin_amdgcn_mfma_f32_16x16x32_bf16(af[m], bfr[n], acc[m][n], 0, 0, 0);
    }
    __syncthreads();
  }
  int r0 = bm * (MW * 64) + wr * 64 + (l4 << 2);
  int c0 = bn * (NB * 32) + wc * (NB * 16) + l15;
  if(EPI == 0){
    unsigned short* dstn[NB];
    float bvn[NB];
    #pragma unroll
    for(int n = 0; n < NB; n++){
      int col = c0 + n * 16;
      bvn[n] = bias[col];
      int which = col / 768, cc = col - which * 768;
      int hd = cc >> 6, dl = cc & 63;
      unsigned short* dst = which == 0 ? o0 : which == 1 ? o1 : o2;
      dstn[n] = dst + (size_t)hd * 65536 + dl;
    }
    #pragma unroll
    for(int m = 0; m < 4; m++){
      #pragma unroll
      for(int j = 0; j < 4; j++){
        int row = r0 + m * 16 + j;
        int bb = row >> 10, sp = row & 1023;
        size_t ro = ((size_t)bb * 12288 + sp) * 64;
        #pragma unroll
        for(int n = 0; n < NB; n++)
          dstn[n][ro] = f2bf(acc[m][n][j] + bvn[n]);
      }
    }
  } else {
    float bvn[NB];
    #pragma unroll
    for(int n = 0; n < NB; n++) bvn[n] = (EPI == 3) ? 0.0f : bias[c0 + n * 16];
    #pragma unroll
    for(int m = 0; m < 4; m++){
      #pragma unroll
      for(int j = 0; j < 4; j++){
        int row = r0 + m * 16 + j;
        #pragma unroll
        for(int n = 0; n < NB; n++){
          int col = c0 + n * 16;
          float v = acc[m][n][j] + bvn[n];
          if(EPI == 1){
            // tanh-form GELU: x * sigmoid(2c(x + 0.044715 x^3)), 2c = 1.59576912
            float t = v * (1.5957691f + 0.07135481f * v * v);
            float gl = v * __builtin_amdgcn_rcpf(1.0f + __expf(-t));
            o0[(size_t)row * N + col] = f2bf(gl);
          } else if(EPI == 2){
            fout[(size_t)row * 768 + col] += v;
          } else {
            fout[(size_t)row * 512 + col] = v;
          }
        }
      }
    }
  }
}

// ---------------- BigBird attention, one block = (b, head, 128 queries) ----------------
// mask: allowed(i,j) = ((j<64) | (i-j<=32)) & (j<=i)
__global__ __launch_bounds__(256)
void k_attn(const unsigned short* __restrict__ qg, const unsigned short* __restrict__ kg,
            const unsigned short* __restrict__ vg, float* __restrict__ h){
  __shared__ unsigned short Vt[64 * 256];      // V^T [d][slot], 16B-chunk XOR swizzled
  __shared__ unsigned short Ps[4][32 * 128];   // per-wave P [32 q][128 slot], swizzled
  int qb = blockIdx.x, bh = blockIdx.y;
  int tid = threadIdx.x, w = tid >> 6, lane = tid & 63;
  int b = bh / 12, hd = bh - b * 12;
  int wbase = qb * 128 - 32;                   // first window key staged
  const unsigned short* vb = vg + (size_t)bh * 1024 * 64;
  for(int u = tid; u < 224 * 8; u += 256){
    int slot = u >> 3, c8 = u & 7;
    int j = slot < 64 ? slot : wbase + (slot - 64);
    if(j < 0) j = 0;
    short8 vv = *(const short8*)(vb + (size_t)j * 64 + c8 * 8);
    #pragma unroll
    for(int e = 0; e < 8; e++){
      int d = c8 * 8 + e;
      Vt[d * 256 + (((slot >> 3) ^ (d & 7)) << 3) + (slot & 7)] = (unsigned short)vv[e];
    }
  }
  __syncthreads();
  int i0 = qb * 128 + 32 * w;
  const unsigned short* qrow = qg + (size_t)bh * 1024 * 64;
  const unsigned short* krow = kg + (size_t)bh * 1024 * 64;
  short8 qf[2][2];
  #pragma unroll
  for(int m = 0; m < 2; m++)
    #pragma unroll
    for(int s = 0; s < 2; s++)
      qf[m][s] = *(const short8*)(qrow + (size_t)(i0 + m * 16 + (lane & 15)) * 64 + s * 32 + ((lane >> 4) << 3));
  f32x4 sacc[2][8] = {};
  #pragma unroll
  for(int n = 0; n < 8; n++){
    int jk = (n < 4) ? (n * 16 + (lane & 15))
                     : (wbase + 32 * w + (n - 4) * 16 + (lane & 15));
    int jc = jk < 0 ? 0 : jk;
    const unsigned short* kr = krow + (size_t)jc * 64 + ((lane >> 4) << 3);
    short8 k0 = *(const short8*)(kr);
    short8 k1 = *(const short8*)(kr + 32);
    #pragma unroll
    for(int m = 0; m < 2; m++){
      sacc[m][n] = __builtin_amdgcn_mfma_f32_16x16x32_bf16(qf[m][0], k0, sacc[m][n], 0, 0, 0);
      sacc[m][n] = __builtin_amdgcn_mfma_f32_16x16x32_bf16(qf[m][1], k1, sacc[m][n], 0, 0, 0);
    }
  }
  #pragma unroll
  for(int m = 0; m < 2; m++)
    #pragma unroll
    for(int n = 0; n < 8; n++){
      int s_ = n * 16 + (lane & 15);
      int jkey = (n < 4) ? s_ : (wbase + 32 * w + (s_ - 64));
      #pragma unroll
      for(int j = 0; j < 4; j++){
        int qi = i0 + m * 16 + ((lane >> 4) << 2) + j;
        bool ok = (n < 4) ? (jkey <= qi)
                          : (jkey >= 64 && jkey <= qi && (qi - jkey) <= 32);
        sacc[m][n][j] = ok ? sacc[m][n][j] * 0.125f : -1e30f;
      }
    }
  float rsum[2][4];
  #pragma unroll
  for(int m = 0; m < 2; m++)
    #pragma unroll
    for(int j = 0; j < 4; j++){
      float mx = sacc[m][0][j];
      #pragma unroll
      for(int n = 1; n < 8; n++) mx = fmaxf(mx, sacc[m][n][j]);
      mx = fmaxf(mx, __shfl_xor(mx, 1)); mx = fmaxf(mx, __shfl_xor(mx, 2));
      mx = fmaxf(mx, __shfl_xor(mx, 4)); mx = fmaxf(mx, __shfl_xor(mx, 8));
      float sm = 0.f;
      #pragma unroll
      for(int n = 0; n < 8; n++){
        float e = expf(sacc[m][n][j] - mx);
        sacc[m][n][j] = e;
        sm += e;
      }
      sm += __shfl_xor(sm, 1); sm += __shfl_xor(sm, 2);
      sm += __shfl_xor(sm, 4); sm += __shfl_xor(sm, 8);
      rsum[m][j] = sm;
    }
  unsigned short* Pw = Ps[w];
  #pragma unroll
  for(int m = 0; m < 2; m++)
    #pragma unroll
    for(int n = 0; n < 8; n++){
      int s_ = n * 16 + (lane & 15);
      #pragma unroll
      for(int j = 0; j < 4; j++){
        int ql = m * 16 + ((lane >> 4) << 2) + j;
        Pw[ql * 128 + (((s_ >> 3) ^ (ql & 7)) << 3) + (s_ & 7)] = f2bf(sacc[m][n][j]);
      }
    }
  f32x4 oacc[2][4] = {};
  #pragma unroll
  for(int s = 0; s < 4; s++){
    short8 pa[2];
    #pragma unroll
    for(int m = 0; m < 2; m++){
      int ql = m * 16 + (lane & 15);
      int ch = s * 4 + (lane >> 4);
      pa[m] = *(const short8*)(Pw + ql * 128 + ((ch ^ (ql & 7)) << 3));
    }
    int kk = s * 32 + ((lane >> 4) << 3);
    int slot0 = kk < 64 ? kk : 64 + 32 * w + (kk - 64);
    #pragma unroll
    for(int n = 0; n < 4; n++){
      int d = n * 16 + (lane & 15);
      short8 vv = *(const short8*)(Vt + d * 256 + (((slot0 >> 3) ^ (d & 7)) << 3));
      #pragma unroll
      for(int m = 0; m < 2; m++)
        oacc[m][n] = __builtin_amdgcn_mfma_f32_16x16x32_bf16(pa[m], vv, oacc[m][n], 0, 0, 0);
    }
  }
  #pragma unroll
  for(int m = 0; m < 2; m++)
    #pragma unroll
    for(int j = 0; j < 4; j++){
      int ql = m * 16 + ((lane >> 4) << 2) + j;
      float inv = 1.0f / rsum[m][j];
      size_t base = ((size_t)(b * 1024 + i0 + ql)) * 768 + hd * 64;
      #pragma unroll
      for(int n = 0; n < 4; n++){
        int d = n * 16 + (lane & 15);
        h[base + d] += oacc[m][n][j] * inv;
      }
    }
}

// ---------------- loss ----------------
__global__ void k_rowloss(const float* __restrict__ pred, const int* __restrict__ tgt,
                          float* __restrict__ rowloss){
  int row = blockIdx.x * 4 + (threadIdx.x >> 6);
  int lane = threadIdx.x & 63;
  const float* p = pred + (size_t)row * 512 + lane * 8;
  float v[8];
  #pragma unroll
  for(int i = 0; i < 8; i++) v[i] = p[i];
  float mx = v[0];
  #pragma unroll
  for(int i = 1; i < 8; i++) mx = fmaxf(mx, v[i]);
  #pragma unroll
  for(int m = 1; m < 64; m <<= 1) mx = fmaxf(mx, __shfl_xor(mx, m));
  float se = 0.f;
  #pragma unroll
  for(int i = 0; i < 8; i++) se += expf(v[i] - mx);
  #pragma unroll
  for(int m = 1; m < 64; m <<= 1) se += __shfl_xor(se, m);
  int t = tgt[row];
  float pt = 0.f;
  int base = lane * 8;
  #pragma unroll
  for(int i = 0; i < 8; i++) pt = (t == base + i) ? v[i] : pt;
  #pragma unroll
  for(int m = 1; m < 64; m <<= 1) pt += __shfl_xor(pt, m);
  if(lane == 0) rowloss[row] = -(pt - mx - logf(se));
}

__global__ void k_lossfinal(const float* __restrict__ rowloss, float* __restrict__ out){
  int tid = threadIdx.x;
  float s = 0.f;
  for(int i = tid; i < 8192; i += 256) s += rowloss[i];
  #pragma unroll
  for(int m = 32; m >= 1; m >>= 1) s += __shfl_xor(s, m);
  __shared__ float red[4];
  if((tid & 63) == 0) red[tid >> 6] = s;
  __syncthreads();
  if(tid == 0) out[0] = (red[0] + red[1] + red[2] + red[3]) * (1.0f / 8192.0f);
}

extern "C" void kernel_launch(void* const* d_in, const int* in_sizes, int n_in,
                              void* d_out, int out_size, void* d_ws, size_t ws_size,
                              hipStream_t stream){
  const int*   x       = (const int*)d_in[0];
  const int*   targets = (const int*)d_in[1];
  const float* wte     = (const float*)d_in[2];
  const float* pos     = (const float*)d_in[3];
  const float* ln1_g   = (const float*)d_in[4];
  const float* ln1_b   = (const float*)d_in[5];
  const float* wq      = (const float*)d_in[6];
  const float* bq      = (const float*)d_in[7];
  const float* wk      = (const float*)d_in[8];
  const float* bk      = (const float*)d_in[9];
  const float* wv      = (const float*)d_in[10];
  const float* bv      = (const float*)d_in[11];
  const float* ln2_g   = (const float*)d_in[12];
  const float* ln2_b   = (const float*)d_in[13];
  const float* w1      = (const float*)d_in[14];
  const float* b1      = (const float*)d_in[15];
  const float* w2      = (const float*)d_in[16];
  const float* b2      = (const float*)d_in[17];
  const float* lnf_g   = (const float*)d_in[18];
  const float* lnf_b   = (const float*)d_in[19];
  const float* w_out   = (const float*)d_in[20];
  float* out = (float*)d_out;

  char* ws = (char*)d_ws;
  float*          h      = (float*)ws;                              // 25,165,824 B
  unsigned short* a_bf   = (unsigned short*)(ws + 25165824);        // 12,582,912 B
  char*           big    = ws + 37748736;                           // 50,331,648 B (qkv | mlp-mid)
  unsigned short* qbf    = (unsigned short*)big;
  unsigned short* kbf    = (unsigned short*)(big + 12582912);
  unsigned short* vbf    = (unsigned short*)(big + 25165824);
  unsigned short* tbf    = (unsigned short*)big;
  // weights: per-layer slot = 12,976,128 B (wqkv_t 3.54MB | w1_t 4.72MB | w2_t 4.72MB)
  bool mega = ws_size >= 192782336ull;              // all-8-layer conversion fits?
  unsigned short* wall   = (unsigned short*)(ws + 88080384);
  size_t wend = 88080384ull + (mega ? 103809024ull : 12976128ull);
  unsigned short* wout_t = (unsigned short*)(ws + wend);            // 786,432 B
  float*          qkvb   = (float*)(ws + wend + 786432);            // 9,216 or 73,728 B
  float*          rowls  = (float*)(ws + wend + 786432 + (mega ? 73728 : 9216));

  if(mega)
    k_convert_all<<<dim3(1585, 8), 256, 0, stream>>>(wq, wk, wv, w1, w2, bq, bk, bv,
                                                     wall, qkvb, 0);
  k_transpose<<<96, 256, 0, stream>>>(w_out, wout_t, 768, 512);     // 6 ty x 16 tx
  k_embed<<<24576, 256, 0, stream>>>(x, wte, pos, h);
  for(int l = 0; l < 8; l++){
    if(!mega)
      k_convert_all<<<dim3(1585, 1), 256, 0, stream>>>(wq, wk, wv, w1, w2, bq, bk, bv,
                                                       wall, qkvb, l);
    int slot = mega ? l : 0;
    unsigned short* wqkv_l = wall + (size_t)slot * 6488064;
    unsigned short* w1_l   = wqkv_l + 1769472;
    unsigned short* w2_l   = w1_l + 2359296;
    float*          qkvb_l = qkvb + slot * 2304;
    k_ln<<<8192, 256, 0, stream>>>(h, ln1_g + l * 768, ln1_b + l * 768, a_bf);
    k_gemm<0,2,4><<<dim3(18, 64), 256, 0, stream>>>(a_bf, wqkv_l, qkvb_l, 768, nullptr, qbf, kbf, vbf);
    k_attn<<<dim3(8, 96), 256, 0, stream>>>(qbf, kbf, vbf, h);
    k_ln<<<8192, 256, 0, stream>>>(h, ln2_g + l * 768, ln2_b + l * 768, a_bf);
    k_gemm<1,2,4><<<dim3(24, 64), 256, 0, stream>>>(a_bf, w1_l, b1 + l * 3072, 768, nullptr, tbf, nullptr, nullptr);
    k_gemm<2,2,2><<<dim3(12, 64), 256, 0, stream>>>(tbf, w2_l, b2 + l * 768, 3072, h, nullptr, nullptr, nullptr);
  }
  k_ln<<<8192, 256, 0, stream>>>(h, lnf_g, lnf_b, a_bf);
  k_gemm<3,2,2><<<dim3(8, 64), 256, 0, stream>>>(a_bf, wout_t, nullptr, 768, out, nullptr, nullptr, nullptr);
  k_rowloss<<<2048, 256, 0, stream>>>(out, targets, rowls);
  k_lossfinal<<<1, 256, 0, stream>>>(rowls, out + 4194304);
}

// Round 9
// 1608.588 us; speedup vs baseline: 1.0507x; 1.0507x over previous
//
#include <hip/hip_runtime.h>
#include <hip/hip_bf16.h>

#define DEV __device__ __forceinline__

typedef __attribute__((ext_vector_type(8))) short short8;
typedef __attribute__((ext_vector_type(4))) float f32x4;

DEV unsigned short f2bf(float f){
  unsigned int u = __builtin_bit_cast(unsigned int, f);
  u += 0x7FFFu + ((u >> 16) & 1u);
  return (unsigned short)(u >> 16);
}

DEV void gld_lds16(const void* g, void* l){
  __builtin_amdgcn_global_load_lds((const __attribute__((address_space(1))) void*)g,
                                   (__attribute__((address_space(3))) void*)l, 16, 0, 0);
}

// ---------------- embedding: h = wte[x] + pos ----------------
__global__ void k_embed(const int* __restrict__ x, const float* __restrict__ wte,
                        const float* __restrict__ pos, float* __restrict__ h){
  int i = blockIdx.x * 256 + threadIdx.x;           // total 8192*768
  int row = i / 768, d = i - row * 768;
  int s = row & 1023;
  h[i] = wte[x[row] * 768 + d] + pos[s * 768 + d];
}

// ---------------- layernorm (f32 in) -> bf16 out ----------------
__global__ void k_ln(const float* __restrict__ src, const float* __restrict__ g,
                     const float* __restrict__ b, unsigned short* __restrict__ out){
  int row = blockIdx.x, t = threadIdx.x;
  const float* p = src + (size_t)row * 768;
  float v0 = p[t], v1 = p[t + 256], v2 = p[t + 512];
  float s = v0 + v1 + v2;
  float sq = v0 * v0 + v1 * v1 + v2 * v2;
  #pragma unroll
  for(int m = 32; m >= 1; m >>= 1){ s += __shfl_xor(s, m); sq += __shfl_xor(sq, m); }
  __shared__ float red[8];
  int w = t >> 6;
  if((t & 63) == 0){ red[w] = s; red[4 + w] = sq; }
  __syncthreads();
  float S  = red[0] + red[1] + red[2] + red[3];
  float SQ = red[4] + red[5] + red[6] + red[7];
  float mu  = S * (1.0f / 768.0f);
  float var = SQ * (1.0f / 768.0f) - mu * mu;
  float inv = rsqrtf(var + 1e-5f);
  unsigned short* o = out + (size_t)row * 768;
  o[t]       = f2bf((v0 - mu) * inv * g[t]       + b[t]);
  o[t + 256] = f2bf((v1 - mu) * inv * g[t + 256] + b[t + 256]);
  o[t + 512] = f2bf((v2 - mu) * inv * g[t + 512] + b[t + 512]);
}

// ------- tiled transpose f32 src[R][C] -> bf16 dst[C][R], 256x32 tiles -------
// read: thread tid reads the full 128B chunk (32 f32) of row r0+tid.
// store: short8 (16B) per lane, 32 lanes -> 512B contiguous per output row.
DEV void tr_tile256(float (*tl)[33], const float* __restrict__ src, unsigned short* __restrict__ dst,
                    int R, int C, int tx, int ty, int tid){
  int r0 = ty * 256, c0 = tx * 32;
  const float* sp = src + (size_t)(r0 + tid) * C + c0;
  #pragma unroll
  for(int e = 0; e < 32; e++) tl[tid][e] = sp[e];
  __syncthreads();
  int lx = tid & 31, ly = tid >> 5;                 // 32 x 8
  #pragma unroll
  for(int j = 0; j < 4; j++){
    int oc = ly + 8 * j;
    short8 pk;
    #pragma unroll
    for(int e = 0; e < 8; e++) pk[e] = (short)f2bf(tl[8 * lx + e][oc]);
    *(short8*)(dst + (size_t)(c0 + oc) * R + r0 + 8 * lx) = pk;
  }
}

// all-layer (or single-layer fallback) weight conversion:
// wq/wk/wv -> wqkv_t[2304][768] bf16, w1 -> w1_t[3072][768], w2 -> w2_t[768][3072],
// qkv bias packed [2304]. blockIdx.y = layer - l0, writes slot blockIdx.y.
// sections (256x32 tiles): qkv 3*(3*24)=216 | w1 3*96=288 | w2 12*24=288 | bias 1 -> 793
__global__ void k_convert_all(const float* __restrict__ wq, const float* __restrict__ wk,
                              const float* __restrict__ wv, const float* __restrict__ w1,
                              const float* __restrict__ w2, const float* __restrict__ bq,
                              const float* __restrict__ bk, const float* __restrict__ bv,
                              unsigned short* __restrict__ wall, float* __restrict__ qkvb,
                              int l0){
  __shared__ float tl[256][33];
  int l = l0 + blockIdx.y, slot = blockIdx.y;
  int bid = blockIdx.x, tid = threadIdx.x;
  unsigned short* wqkv_t = wall + (size_t)slot * 6488064;
  unsigned short* w1_t   = wqkv_t + 1769472;
  unsigned short* w2_t   = w1_t + 2359296;
  float* qb = qkvb + slot * 2304;
  const float* wq_l = wq + (size_t)l * 589824;
  const float* wk_l = wk + (size_t)l * 589824;
  const float* wv_l = wv + (size_t)l * 589824;
  const float* w1_l = w1 + (size_t)l * 2359296;
  const float* w2_l = w2 + (size_t)l * 2359296;
  if(bid < 216){
    int which = bid / 72, t = bid - which * 72;     // 3 ty x 24 tx tiles of 768x768
    const float* src = which == 0 ? wq_l : which == 1 ? wk_l : wv_l;
    tr_tile256(tl, src, wqkv_t + (size_t)which * 589824, 768, 768, t % 24, t / 24, tid);
  } else if(bid < 216 + 288){
    int t = bid - 216;                              // 3 ty x 96 tx tiles of 768x3072
    tr_tile256(tl, w1_l, w1_t, 768, 3072, t % 96, t / 96, tid);
  } else if(bid < 216 + 576){
    int t = bid - 504;                              // 12 ty x 24 tx tiles of 3072x768
    tr_tile256(tl, w2_l, w2_t, 3072, 768, t % 24, t / 24, tid);
  } else {
    for(int i = tid; i < 768; i += 256){
      qb[i] = bq[l * 768 + i]; qb[768 + i] = bk[l * 768 + i]; qb[1536 + i] = bv[l * 768 + i];
    }
  }
}

__global__ void k_transpose(const float* __restrict__ src, unsigned short* __restrict__ dst,
                            int R, int C){
  __shared__ float tl[256][33];
  int nx = C / 32;
  tr_tile256(tl, src, dst, R, C, blockIdx.x % nx, blockIdx.x / nx, threadIdx.x);
}

// ---------------- bf16 GEMM: C[M,N] = A[M,K] * Bt[N,K]^T  (+ fused epilogue) ----------------
// m97 loop; tile BM = MW*64 rows x BN = NB*32 cols, MW*2 waves (MW rows x 2 cols of waves),
// per-wave 64 x NB*16. BK=64, single-buffer 2-barrier, global_load_lds w=16, T2 pre-swizzled
// source, T1 XCD-chunked block swizzle (requires nwg%8==0).
// MW=4 (512 thr, 48KB LDS): high MACs/staged-byte for the big-N GEMMs.
// MW=2 NB=2 (256 thr, 24KB): occupancy-friendly for small-N (MLP2, logits).
// EPI 0: +bias, split q/k/v [B*H,S,64] bf16 | 1: +bias fast-GELU bf16 | 2: +bias h+= | 3: f32 out
template<int EPI, int MW, int NB>
__global__ __launch_bounds__(MW * 128, 4)
void k_gemm(const unsigned short* __restrict__ A, const unsigned short* __restrict__ Bt,
            const float* __restrict__ bias, int K,
            float* __restrict__ fout, unsigned short* __restrict__ o0,
            unsigned short* __restrict__ o1, unsigned short* __restrict__ o2){
  constexpr int THREADS = MW * 128;
  constexpr int AL = 4;                 // A gld_lds per thread
  constexpr int BL = (2 * NB) / MW;     // B gld_lds per thread
  __shared__ unsigned short As[MW * 64 * 64];
  __shared__ unsigned short Bs[NB * 32 * 64];
  int tid = threadIdx.x, w = tid >> 6, lane = tid & 63;
  int l15 = lane & 15, l4 = lane >> 4;
  int nbx = gridDim.x;
  int bid = blockIdx.y * nbx + blockIdx.x;
  int cpx = (nbx * gridDim.y) >> 3;
  int sid = (bid & 7) * cpx + (bid >> 3);       // XCD k owns sids [k*cpx,(k+1)*cpx)
  int bm = sid / nbx, bn = sid - bm * nbx;      // bm-major within chunk -> A-panel/XCD locality
  int N = nbx * NB * 32;
  int wr = w >> 1, wc = w & 1;
  f32x4 acc[4][NB] = {};
  int rowA[AL], colA[AL], rowB[BL], colB[BL];
  #pragma unroll
  for(int i = 0; i < AL; i++){
    int o = i * THREADS * 16 + tid * 16;
    int r = o >> 7, ch = (o >> 4) & 7;
    rowA[i] = r; colA[i] = ((ch ^ (r & 7)) << 3);
  }
  #pragma unroll
  for(int i = 0; i < BL; i++){
    int o = i * THREADS * 16 + tid * 16;
    int r = o >> 7, ch = (o >> 4) & 7;
    rowB[i] = r; colB[i] = ((ch ^ (r & 7)) << 3);
  }
  const size_t aBase = (size_t)bm * (MW * 64);
  const size_t bBase = (size_t)bn * (NB * 32);
  for(int kt = 0; kt < K; kt += 64){
    #pragma unroll
    for(int i = 0; i < AL; i++)
      gld_lds16(A + (aBase + rowA[i]) * K + kt + colA[i],
                (char*)As + i * THREADS * 16 + tid * 16);
    #pragma unroll
    for(int i = 0; i < BL; i++)
      gld_lds16(Bt + (bBase + rowB[i]) * K + kt + colB[i],
                (char*)Bs + i * THREADS * 16 + tid * 16);
    __syncthreads();
    #pragma unroll
    for(int s = 0; s < 2; s++){
      short8 af[4], bfr[NB];
      #pragma unroll
      for(int m = 0; m < 4; m++){
        int r = wr * 64 + m * 16 + l15;
        int ch = s * 4 + l4;
        af[m] = *(const short8*)(As + r * 64 + ((ch ^ (r & 7)) << 3));
      }
      #pragma unroll
      for(int n = 0; n < NB; n++){
        int r = wc * (NB * 16) + n * 16 + l15;
        int ch = s * 4 + l4;
        bfr[n] = *(const short8*)(Bs + r * 64 + ((ch ^ (r & 7)) << 3));
      }
      #pragma unroll
      for(int m = 0; m < 4; m++)
        #pragma unroll
        for(int n = 0; n < NB; n++)
          acc[m][n] = __builtin_amdgcn_mfma_f32_16x16x32_bf16(af[m], bfr[n], acc[m][n], 0, 0, 0);
    }
    __syncthreads();
  }
  int r0 = bm * (MW * 64) + wr * 64 + (l4 << 2);
  int c0 = bn * (NB * 32) + wc * (NB * 16) + l15;
  if(EPI == 0){
    unsigned short* dstn[NB];
    float bvn[NB];
    #pragma unroll
    for(int n = 0; n < NB; n++){
      int col = c0 + n * 16;
      bvn[n] = bias[col];
      int which = col / 768, cc = col - which * 768;
      int hd = cc >> 6, dl = cc & 63;
      unsigned short* dst = which == 0 ? o0 : which == 1 ? o1 : o2;
      dstn[n] = dst + (size_t)hd * 65536 + dl;
    }
    #pragma unroll
    for(int m = 0; m < 4; m++){
      #pragma unroll
      for(int j = 0; j < 4; j++){
        int row = r0 + m * 16 + j;
        int bb = row >> 10, sp = row & 1023;
        size_t ro = ((size_t)bb * 12288 + sp) * 64;
        #pragma unroll
        for(int n = 0; n < NB; n++)
          dstn[n][ro] = f2bf(acc[m][n][j] + bvn[n]);
      }
    }
  } else {
    float bvn[NB];
    #pragma unroll
    for(int n = 0; n < NB; n++) bvn[n] = (EPI == 3) ? 0.0f : bias[c0 + n * 16];
    #pragma unroll
    for(int m = 0; m < 4; m++){
      #pragma unroll
      for(int j = 0; j < 4; j++){
        int row = r0 + m * 16 + j;
        #pragma unroll
        for(int n = 0; n < NB; n++){
          int col = c0 + n * 16;
          float v = acc[m][n][j] + bvn[n];
          if(EPI == 1){
            // tanh-form GELU: x * sigmoid(2c(x + 0.044715 x^3)), 2c = 1.59576912
            float t = v * (1.5957691f + 0.07135481f * v * v);
            float gl = v * __builtin_amdgcn_rcpf(1.0f + __expf(-t));
            o0[(size_t)row * N + col] = f2bf(gl);
          } else if(EPI == 2){
            fout[(size_t)row * 768 + col] += v;
          } else {
            fout[(size_t)row * 512 + col] = v;
          }
        }
      }
    }
  }
}

// ---------------- BigBird attention, one block = (b, head, 128 queries) ----------------
// mask: allowed(i,j) = ((j<64) | (i-j<=32)) & (j<=i)
__global__ __launch_bounds__(256)
void k_attn(const unsigned short* __restrict__ qg, const unsigned short* __restrict__ kg,
            const unsigned short* __restrict__ vg, float* __restrict__ h){
  __shared__ unsigned short Vt[64 * 256];      // V^T [d][slot], 16B-chunk XOR swizzled
  __shared__ unsigned short Ps[4][32 * 128];   // per-wave P [32 q][128 slot], swizzled
  int qb = blockIdx.x, bh = blockIdx.y;
  int tid = threadIdx.x, w = tid >> 6, lane = tid & 63;
  int b = bh / 12, hd = bh - b * 12;
  int wbase = qb * 128 - 32;                   // first window key staged
  const unsigned short* vb = vg + (size_t)bh * 1024 * 64;
  for(int u = tid; u < 224 * 8; u += 256){
    int slot = u >> 3, c8 = u & 7;
    int j = slot < 64 ? slot : wbase + (slot - 64);
    if(j < 0) j = 0;
    short8 vv = *(const short8*)(vb + (size_t)j * 64 + c8 * 8);
    #pragma unroll
    for(int e = 0; e < 8; e++){
      int d = c8 * 8 + e;
      Vt[d * 256 + (((slot >> 3) ^ (d & 7)) << 3) + (slot & 7)] = (unsigned short)vv[e];
    }
  }
  __syncthreads();
  int i0 = qb * 128 + 32 * w;
  const unsigned short* qrow = qg + (size_t)bh * 1024 * 64;
  const unsigned short* krow = kg + (size_t)bh * 1024 * 64;
  short8 qf[2][2];
  #pragma unroll
  for(int m = 0; m < 2; m++)
    #pragma unroll
    for(int s = 0; s < 2; s++)
      qf[m][s] = *(const short8*)(qrow + (size_t)(i0 + m * 16 + (lane & 15)) * 64 + s * 32 + ((lane >> 4) << 3));
  f32x4 sacc[2][8] = {};
  #pragma unroll
  for(int n = 0; n < 8; n++){
    int jk = (n < 4) ? (n * 16 + (lane & 15))
                     : (wbase + 32 * w + (n - 4) * 16 + (lane & 15));
    int jc = jk < 0 ? 0 : jk;
    const unsigned short* kr = krow + (size_t)jc * 64 + ((lane >> 4) << 3);
    short8 k0 = *(const short8*)(kr);
    short8 k1 = *(const short8*)(kr + 32);
    #pragma unroll
    for(int m = 0; m < 2; m++){
      sacc[m][n] = __builtin_amdgcn_mfma_f32_16x16x32_bf16(qf[m][0], k0, sacc[m][n], 0, 0, 0);
      sacc[m][n] = __builtin_amdgcn_mfma_f32_16x16x32_bf16(qf[m][1], k1, sacc[m][n], 0, 0, 0);
    }
  }
  #pragma unroll
  for(int m = 0; m < 2; m++)
    #pragma unroll
    for(int n = 0; n < 8; n++){
      int s_ = n * 16 + (lane & 15);
      int jkey = (n < 4) ? s_ : (wbase + 32 * w + (s_ - 64));
      #pragma unroll
      for(int j = 0; j < 4; j++){
        int qi = i0 + m * 16 + ((lane >> 4) << 2) + j;
        bool ok = (n < 4) ? (jkey <= qi)
                          : (jkey >= 64 && jkey <= qi && (qi - jkey) <= 32);
        sacc[m][n][j] = ok ? sacc[m][n][j] * 0.125f : -1e30f;
      }
    }
  float rsum[2][4];
  #pragma unroll
  for(int m = 0; m < 2; m++)
    #pragma unroll
    for(int j = 0; j < 4; j++){
      float mx = sacc[m][0][j];
      #pragma unroll
      for(int n = 1; n < 8; n++) mx = fmaxf(mx, sacc[m][n][j]);
      mx = fmaxf(mx, __shfl_xor(mx, 1)); mx = fmaxf(mx, __shfl_xor(mx, 2));
      mx = fmaxf(mx, __shfl_xor(mx, 4)); mx = fmaxf(mx, __shfl_xor(mx, 8));
      float sm = 0.f;
      #pragma unroll
      for(int n = 0; n < 8; n++){
        float e = expf(sacc[m][n][j] - mx);
        sacc[m][n][j] = e;
        sm += e;
      }
      sm += __shfl_xor(sm, 1); sm += __shfl_xor(sm, 2);
      sm += __shfl_xor(sm, 4); sm += __shfl_xor(sm, 8);
      rsum[m][j] = sm;
    }
  unsigned short* Pw = Ps[w];
  #pragma unroll
  for(int m = 0; m < 2; m++)
    #pragma unroll
    for(int n = 0; n < 8; n++){
      int s_ = n * 16 + (lane & 15);
      #pragma unroll
      for(int j = 0; j < 4; j++){
        int ql = m * 16 + ((lane >> 4) << 2) + j;
        Pw[ql * 128 + (((s_ >> 3) ^ (ql & 7)) << 3) + (s_ & 7)] = f2bf(sacc[m][n][j]);
      }
    }
  f32x4 oacc[2][4] = {};
  #pragma unroll
  for(int s = 0; s < 4; s++){
    short8 pa[2];
    #pragma unroll
    for(int m = 0; m < 2; m++){
      int ql = m * 16 + (lane & 15);
      int ch = s * 4 + (lane >> 4);
      pa[m] = *(const short8*)(Pw + ql * 128 + ((ch ^ (ql & 7)) << 3));
    }
    int kk = s * 32 + ((lane >> 4) << 3);
    int slot0 = kk < 64 ? kk : 64 + 32 * w + (kk - 64);
    #pragma unroll
    for(int n = 0; n < 4; n++){
      int d = n * 16 + (lane & 15);
      short8 vv = *(const short8*)(Vt + d * 256 + (((slot0 >> 3) ^ (d & 7)) << 3));
      #pragma unroll
      for(int m = 0; m < 2; m++)
        oacc[m][n] = __builtin_amdgcn_mfma_f32_16x16x32_bf16(pa[m], vv, oacc[m][n], 0, 0, 0);
    }
  }
  #pragma unroll
  for(int m = 0; m < 2; m++)
    #pragma unroll
    for(int j = 0; j < 4; j++){
      int ql = m * 16 + ((lane >> 4) << 2) + j;
      float inv = 1.0f / rsum[m][j];
      size_t base = ((size_t)(b * 1024 + i0 + ql)) * 768 + hd * 64;
      #pragma unroll
      for(int n = 0; n < 4; n++){
        int d = n * 16 + (lane & 15);
        h[base + d] += oacc[m][n][j] * inv;
      }
    }
}

// ---------------- loss ----------------
__global__ void k_rowloss(const float* __restrict__ pred, const int* __restrict__ tgt,
                          float* __restrict__ rowloss){
  int row = blockIdx.x * 4 + (threadIdx.x >> 6);
  int lane = threadIdx.x & 63;
  const float* p = pred + (size_t)row * 512 + lane * 8;
  float v[8];
  #pragma unroll
  for(int i = 0; i < 8; i++) v[i] = p[i];
  float mx = v[0];
  #pragma unroll
  for(int i = 1; i < 8; i++) mx = fmaxf(mx, v[i]);
  #pragma unroll
  for(int m = 1; m < 64; m <<= 1) mx = fmaxf(mx, __shfl_xor(mx, m));
  float se = 0.f;
  #pragma unroll
  for(int i = 0; i < 8; i++) se += expf(v[i] - mx);
  #pragma unroll
  for(int m = 1; m < 64; m <<= 1) se += __shfl_xor(se, m);
  int t = tgt[row];
  float pt = 0.f;
  int base = lane * 8;
  #pragma unroll
  for(int i = 0; i < 8; i++) pt = (t == base + i) ? v[i] : pt;
  #pragma unroll
  for(int m = 1; m < 64; m <<= 1) pt += __shfl_xor(pt, m);
  if(lane == 0) rowloss[row] = -(pt - mx - logf(se));
}

__global__ void k_lossfinal(const float* __restrict__ rowloss, float* __restrict__ out){
  int tid = threadIdx.x;
  float s = 0.f;
  for(int i = tid; i < 8192; i += 256) s += rowloss[i];
  #pragma unroll
  for(int m = 32; m >= 1; m >>= 1) s += __shfl_xor(s, m);
  __shared__ float red[4];
  if((tid & 63) == 0) red[tid >> 6] = s;
  __syncthreads();
  if(tid == 0) out[0] = (red[0] + red[1] + red[2] + red[3]) * (1.0f / 8192.0f);
}

extern "C" void kernel_launch(void* const* d_in, const int* in_sizes, int n_in,
                              void* d_out, int out_size, void* d_ws, size_t ws_size,
                              hipStream_t stream){
  const int*   x       = (const int*)d_in[0];
  const int*   targets = (const int*)d_in[1];
  const float* wte     = (const float*)d_in[2];
  const float* pos     = (const float*)d_in[3];
  const float* ln1_g   = (const float*)d_in[4];
  const float* ln1_b   = (const float*)d_in[5];
  const float* wq      = (const float*)d_in[6];
  const float* bq      = (const float*)d_in[7];
  const float* wk      = (const float*)d_in[8];
  const float* bk      = (const float*)d_in[9];
  const float* wv      = (const float*)d_in[10];
  const float* bv      = (const float*)d_in[11];
  const float* ln2_g   = (const float*)d_in[12];
  const float* ln2_b   = (const float*)d_in[13];
  const float* w1      = (const float*)d_in[14];
  const float* b1      = (const float*)d_in[15];
  const float* w2      = (const float*)d_in[16];
  const float* b2      = (const float*)d_in[17];
  const float* lnf_g   = (const float*)d_in[18];
  const float* lnf_b   = (const float*)d_in[19];
  const float* w_out   = (const float*)d_in[20];
  float* out = (float*)d_out;

  char* ws = (char*)d_ws;
  float*          h      = (float*)ws;                              // 25,165,824 B
  unsigned short* a_bf   = (unsigned short*)(ws + 25165824);        // 12,582,912 B
  char*           big    = ws + 37748736;                           // 50,331,648 B (qkv | mlp-mid)
  unsigned short* qbf    = (unsigned short*)big;
  unsigned short* kbf    = (unsigned short*)(big + 12582912);
  unsigned short* vbf    = (unsigned short*)(big + 25165824);
  unsigned short* tbf    = (unsigned short*)big;
  // weights: per-layer slot = 12,976,128 B (wqkv_t 3.54MB | w1_t 4.72MB | w2_t 4.72MB)
  bool mega = ws_size >= 192782336ull;              // all-8-layer conversion fits?
  unsigned short* wall   = (unsigned short*)(ws + 88080384);
  size_t wend = 88080384ull + (mega ? 103809024ull : 12976128ull);
  unsigned short* wout_t = (unsigned short*)(ws + wend);            // 786,432 B
  float*          qkvb   = (float*)(ws + wend + 786432);            // 9,216 or 73,728 B
  float*          rowls  = (float*)(ws + wend + 786432 + (mega ? 73728 : 9216));

  if(mega)
    k_convert_all<<<dim3(793, 8), 256, 0, stream>>>(wq, wk, wv, w1, w2, bq, bk, bv,
                                                    wall, qkvb, 0);
  k_transpose<<<48, 256, 0, stream>>>(w_out, wout_t, 768, 512);     // 3 ty x 16 tx
  k_embed<<<24576, 256, 0, stream>>>(x, wte, pos, h);
  for(int l = 0; l < 8; l++){
    if(!mega)
      k_convert_all<<<dim3(793, 1), 256, 0, stream>>>(wq, wk, wv, w1, w2, bq, bk, bv,
                                                      wall, qkvb, l);
    int slot = mega ? l : 0;
    unsigned short* wqkv_l = wall + (size_t)slot * 6488064;
    unsigned short* w1_l   = wqkv_l + 1769472;
    unsigned short* w2_l   = w1_l + 2359296;
    float*          qkvb_l = qkvb + slot * 2304;
    k_ln<<<8192, 256, 0, stream>>>(h, ln1_g + l * 768, ln1_b + l * 768, a_bf);
    k_gemm<0,4,4><<<dim3(18, 32), 512, 0, stream>>>(a_bf, wqkv_l, qkvb_l, 768, nullptr, qbf, kbf, vbf);
    k_attn<<<dim3(8, 96), 256, 0, stream>>>(qbf, kbf, vbf, h);
    k_ln<<<8192, 256, 0, stream>>>(h, ln2_g + l * 768, ln2_b + l * 768, a_bf);
    k_gemm<1,4,4><<<dim3(24, 32), 512, 0, stream>>>(a_bf, w1_l, b1 + l * 3072, 768, nullptr, tbf, nullptr, nullptr);
    k_gemm<2,2,2><<<dim3(12, 64), 256, 0, stream>>>(tbf, w2_l, b2 + l * 768, 3072, h, nullptr, nullptr, nullptr);
  }
  k_ln<<<8192, 256, 0, stream>>>(h, lnf_g, lnf_b, a_bf);
  k_gemm<3,2,2><<<dim3(8, 64), 256, 0, stream>>>(a_bf, wout_t, nullptr, 768, out, nullptr, nullptr, nullptr);
  k_rowloss<<<2048, 256, 0, stream>>>(out, targets, rowls);
  k_lossfinal<<<1, 256, 0, stream>>>(rowls, out + 4194304);
}

// Round 10
// 1578.062 us; speedup vs baseline: 1.0710x; 1.0193x over previous
//
#include <hip/hip_runtime.h>
#include <hip/hip_bf16.h>

#define DEV __device__ __forceinline__

typedef __attribute__((ext_vector_type(8))) short short8;
typedef __attribute__((ext_vector_type(4))) float f32x4;

DEV unsigned short f2bf(float f){
  unsigned int u = __builtin_bit_cast(unsigned int, f);
  u += 0x7FFFu + ((u >> 16) & 1u);
  return (unsigned short)(u >> 16);
}

DEV void gld_lds16(const void* g, void* l){
  __builtin_amdgcn_global_load_lds((const __attribute__((address_space(1))) void*)g,
                                   (__attribute__((address_space(3))) void*)l, 16, 0, 0);
}

// ---------------- embedding: h = wte[x] + pos (float4) ----------------
__global__ void k_embed(const int* __restrict__ x, const float* __restrict__ wte,
                        const float* __restrict__ pos, float* __restrict__ h){
  int i4 = (blockIdx.x * 256 + threadIdx.x) * 4;    // total 8192*768, 768%4==0
  int row = i4 / 768, d = i4 - row * 768;
  int s = row & 1023;
  f32x4 a = *(const f32x4*)(wte + (size_t)x[row] * 768 + d);
  f32x4 p = *(const f32x4*)(pos + s * 768 + d);
  #pragma unroll
  for(int e = 0; e < 4; e++) a[e] += p[e];
  *(f32x4*)(h + i4) = a;
}

// ---------------- layernorm: wave-per-row, float4 loads, barrier-free ----------------
__global__ void k_ln(const float* __restrict__ src, const float* __restrict__ g,
                     const float* __restrict__ b, unsigned short* __restrict__ out){
  int w = threadIdx.x >> 6, lane = threadIdx.x & 63;
  int row = blockIdx.x * 4 + w;
  const float* p = src + (size_t)row * 768;
  f32x4 v[3];
  #pragma unroll
  for(int k = 0; k < 3; k++) v[k] = *(const f32x4*)(p + k * 256 + lane * 4);
  float s = 0.f, sq = 0.f;
  #pragma unroll
  for(int k = 0; k < 3; k++)
    #pragma unroll
    for(int e = 0; e < 4; e++){ s += v[k][e]; sq += v[k][e] * v[k][e]; }
  #pragma unroll
  for(int m = 32; m >= 1; m >>= 1){ s += __shfl_xor(s, m); sq += __shfl_xor(sq, m); }
  float mu  = s * (1.0f / 768.0f);
  float inv = rsqrtf(sq * (1.0f / 768.0f) - mu * mu + 1e-5f);
  unsigned short* o = out + (size_t)row * 768;
  #pragma unroll
  for(int k = 0; k < 3; k++){
    f32x4 gg = *(const f32x4*)(g + k * 256 + lane * 4);
    f32x4 bb = *(const f32x4*)(b + k * 256 + lane * 4);
    unsigned long long pk =
        (unsigned long long)f2bf((v[k][0] - mu) * inv * gg[0] + bb[0]) |
        ((unsigned long long)f2bf((v[k][1] - mu) * inv * gg[1] + bb[1]) << 16) |
        ((unsigned long long)f2bf((v[k][2] - mu) * inv * gg[2] + bb[2]) << 32) |
        ((unsigned long long)f2bf((v[k][3] - mu) * inv * gg[3] + bb[3]) << 48);
    *(unsigned long long*)(o + k * 256 + lane * 4) = pk;
  }
}

// ------- tiled transpose f32 src[R][C] -> bf16 dst[C][R], 256x32 tiles -------
DEV void tr_tile256(float (*tl)[33], const float* __restrict__ src, unsigned short* __restrict__ dst,
                    int R, int C, int tx, int ty, int tid){
  int r0 = ty * 256, c0 = tx * 32;
  const float* sp = src + (size_t)(r0 + tid) * C + c0;
  #pragma unroll
  for(int e = 0; e < 32; e++) tl[tid][e] = sp[e];
  __syncthreads();
  int lx = tid & 31, ly = tid >> 5;                 // 32 x 8
  #pragma unroll
  for(int j = 0; j < 4; j++){
    int oc = ly + 8 * j;
    short8 pk;
    #pragma unroll
    for(int e = 0; e < 8; e++) pk[e] = (short)f2bf(tl[8 * lx + e][oc]);
    *(short8*)(dst + (size_t)(c0 + oc) * R + r0 + 8 * lx) = pk;
  }
}

// weight conversion; layer l = l0 + blockIdx.y, slot = slot0 + blockIdx.y.
// sections (256x32 tiles): qkv 3*(3*24)=216 | w1 3*96=288 | w2 12*24=288 | bias 1 -> 793
__global__ void k_convert_all(const float* __restrict__ wq, const float* __restrict__ wk,
                              const float* __restrict__ wv, const float* __restrict__ w1,
                              const float* __restrict__ w2, const float* __restrict__ bq,
                              const float* __restrict__ bk, const float* __restrict__ bv,
                              unsigned short* __restrict__ wall, float* __restrict__ qkvb,
                              int l0, int slot0){
  __shared__ float tl[256][33];
  int l = l0 + blockIdx.y, slot = slot0 + blockIdx.y;
  int bid = blockIdx.x, tid = threadIdx.x;
  unsigned short* wqkv_t = wall + (size_t)slot * 6488064;
  unsigned short* w1_t   = wqkv_t + 1769472;
  unsigned short* w2_t   = w1_t + 2359296;
  float* qb = qkvb + slot * 2304;
  const float* wq_l = wq + (size_t)l * 589824;
  const float* wk_l = wk + (size_t)l * 589824;
  const float* wv_l = wv + (size_t)l * 589824;
  const float* w1_l = w1 + (size_t)l * 2359296;
  const float* w2_l = w2 + (size_t)l * 2359296;
  if(bid < 216){
    int which = bid / 72, t = bid - which * 72;     // 3 ty x 24 tx tiles of 768x768
    const float* src = which == 0 ? wq_l : which == 1 ? wk_l : wv_l;
    tr_tile256(tl, src, wqkv_t + (size_t)which * 589824, 768, 768, t % 24, t / 24, tid);
  } else if(bid < 216 + 288){
    int t = bid - 216;                              // 3 ty x 96 tx tiles of 768x3072
    tr_tile256(tl, w1_l, w1_t, 768, 3072, t % 96, t / 96, tid);
  } else if(bid < 216 + 576){
    int t = bid - 504;                              // 12 ty x 24 tx tiles of 3072x768
    tr_tile256(tl, w2_l, w2_t, 3072, 768, t % 24, t / 24, tid);
  } else {
    for(int i = tid; i < 768; i += 256){
      qb[i] = bq[l * 768 + i]; qb[768 + i] = bk[l * 768 + i]; qb[1536 + i] = bv[l * 768 + i];
    }
  }
}

__global__ void k_transpose(const float* __restrict__ src, unsigned short* __restrict__ dst,
                            int R, int C){
  __shared__ float tl[256][33];
  int nx = C / 32;
  tr_tile256(tl, src, dst, R, C, blockIdx.x % nx, blockIdx.x / nx, threadIdx.x);
}

// ---------------- bf16 GEMM: C[M,N] = A[M,K] * Bt[N,K]^T  (+ fused epilogue) ----------------
// m97 loop; tile BM = MW*64 rows x BN = NB*32 cols, MW*2 waves (MW rows x 2 cols of waves),
// per-wave 64 x NB*16. BK=64, single-buffer 2-barrier, global_load_lds w=16, T2 pre-swizzled
// source, T1 XCD-chunked block swizzle (requires nwg%8==0).
// MW=4 (512 thr, 48KB LDS): high MACs/staged-byte for the big-N GEMMs.
// MW=2 NB=2 (256 thr, 24KB): occupancy-friendly for small-N (MLP2, logits).
// EPI 0: +bias, split q/k/v [B*H,S,64] bf16 | 1: +bias fast-GELU bf16 | 2: +bias h+= | 3: f32 out
template<int EPI, int MW, int NB>
__global__ __launch_bounds__(MW * 128, 4)
void k_gemm(const unsigned short* __restrict__ A, const unsigned short* __restrict__ Bt,
            const float* __restrict__ bias, int K,
            float* __restrict__ fout, unsigned short* __restrict__ o0,
            unsigned short* __restrict__ o1, unsigned short* __restrict__ o2){
  constexpr int THREADS = MW * 128;
  constexpr int AL = 4;                 // A gld_lds per thread
  constexpr int BL = (2 * NB) / MW;     // B gld_lds per thread
  __shared__ unsigned short As[MW * 64 * 64];
  __shared__ unsigned short Bs[NB * 32 * 64];
  int tid = threadIdx.x, w = tid >> 6, lane = tid & 63;
  int l15 = lane & 15, l4 = lane >> 4;
  int nbx = gridDim.x;
  int bid = blockIdx.y * nbx + blockIdx.x;
  int cpx = (nbx * gridDim.y) >> 3;
  int sid = (bid & 7) * cpx + (bid >> 3);       // XCD k owns sids [k*cpx,(k+1)*cpx)
  int bm = sid / nbx, bn = sid - bm * nbx;      // bm-major within chunk -> A-panel/XCD locality
  int N = nbx * NB * 32;
  int wr = w >> 1, wc = w & 1;
  f32x4 acc[4][NB] = {};
  int rowA[AL], colA[AL], rowB[BL], colB[BL];
  #pragma unroll
  for(int i = 0; i < AL; i++){
    int o = i * THREADS * 16 + tid * 16;
    int r = o >> 7, ch = (o >> 4) & 7;
    rowA[i] = r; colA[i] = ((ch ^ (r & 7)) << 3);
  }
  #pragma unroll
  for(int i = 0; i < BL; i++){
    int o = i * THREADS * 16 + tid * 16;
    int r = o >> 7, ch = (o >> 4) & 7;
    rowB[i] = r; colB[i] = ((ch ^ (r & 7)) << 3);
  }
  const size_t aBase = (size_t)bm * (MW * 64);
  const size_t bBase = (size_t)bn * (NB * 32);
  for(int kt = 0; kt < K; kt += 64){
    #pragma unroll
    for(int i = 0; i < AL; i++)
      gld_lds16(A + (aBase + rowA[i]) * K + kt + colA[i],
                (char*)As + i * THREADS * 16 + tid * 16);
    #pragma unroll
    for(int i = 0; i < BL; i++)
      gld_lds16(Bt + (bBase + rowB[i]) * K + kt + colB[i],
                (char*)Bs + i * THREADS * 16 + tid * 16);
    __syncthreads();
    #pragma unroll
    for(int s = 0; s < 2; s++){
      short8 af[4], bfr[NB];
      #pragma unroll
      for(int m = 0; m < 4; m++){
        int r = wr * 64 + m * 16 + l15;
        int ch = s * 4 + l4;
        af[m] = *(const short8*)(As + r * 64 + ((ch ^ (r & 7)) << 3));
      }
      #pragma unroll
      for(int n = 0; n < NB; n++){
        int r = wc * (NB * 16) + n * 16 + l15;
        int ch = s * 4 + l4;
        bfr[n] = *(const short8*)(Bs + r * 64 + ((ch ^ (r & 7)) << 3));
      }
      #pragma unroll
      for(int m = 0; m < 4; m++)
        #pragma unroll
        for(int n = 0; n < NB; n++)
          acc[m][n] = __builtin_amdgcn_mfma_f32_16x16x32_bf16(af[m], bfr[n], acc[m][n], 0, 0, 0);
    }
    __syncthreads();
  }
  int r0 = bm * (MW * 64) + wr * 64 + (l4 << 2);
  int c0 = bn * (NB * 32) + wc * (NB * 16) + l15;
  if(EPI == 0){
    unsigned short* dstn[NB];
    float bvn[NB];
    #pragma unroll
    for(int n = 0; n < NB; n++){
      int col = c0 + n * 16;
      bvn[n] = bias[col];
      int which = col / 768, cc = col - which * 768;
      int hd = cc >> 6, dl = cc & 63;
      unsigned short* dst = which == 0 ? o0 : which == 1 ? o1 : o2;
      dstn[n] = dst + (size_t)hd * 65536 + dl;
    }
    #pragma unroll
    for(int m = 0; m < 4; m++){
      #pragma unroll
      for(int j = 0; j < 4; j++){
        int row = r0 + m * 16 + j;
        int bb = row >> 10, sp = row & 1023;
        size_t ro = ((size_t)bb * 12288 + sp) * 64;
        #pragma unroll
        for(int n = 0; n < NB; n++)
          dstn[n][ro] = f2bf(acc[m][n][j] + bvn[n]);
      }
    }
  } else {
    float bvn[NB];
    #pragma unroll
    for(int n = 0; n < NB; n++) bvn[n] = (EPI == 3) ? 0.0f : bias[c0 + n * 16];
    #pragma unroll
    for(int m = 0; m < 4; m++){
      #pragma unroll
      for(int j = 0; j < 4; j++){
        int row = r0 + m * 16 + j;
        #pragma unroll
        for(int n = 0; n < NB; n++){
          int col = c0 + n * 16;
          float v = acc[m][n][j] + bvn[n];
          if(EPI == 1){
            // tanh-form GELU: x * sigmoid(2c(x + 0.044715 x^3)), 2c = 1.59576912
            float t = v * (1.5957691f + 0.07135481f * v * v);
            float gl = v * __builtin_amdgcn_rcpf(1.0f + __expf(-t));
            o0[(size_t)row * N + col] = f2bf(gl);
          } else if(EPI == 2){
            fout[(size_t)row * 768 + col] += v;
          } else {
            fout[(size_t)row * 512 + col] = v;
          }
        }
      }
    }
  }
}

// ---------------- BigBird attention, one block = (b, head, 128 queries) ----------------
// mask: allowed(i,j) = ((j<64) | (i-j<=32)) & (j<=i)
__global__ __launch_bounds__(256)
void k_attn(const unsigned short* __restrict__ qg, const unsigned short* __restrict__ kg,
            const unsigned short* __restrict__ vg, float* __restrict__ h){
  __shared__ unsigned short Vt[64 * 256];      // V^T [d][slot], 16B-chunk XOR swizzled
  __shared__ unsigned short Ps[4][32 * 128];   // per-wave P [32 q][128 slot], swizzled
  int qb = blockIdx.x, bh = blockIdx.y;
  int tid = threadIdx.x, w = tid >> 6, lane = tid & 63;
  int b = bh / 12, hd = bh - b * 12;
  int wbase = qb * 128 - 32;                   // first window key staged
  const unsigned short* vb = vg + (size_t)bh * 1024 * 64;
  for(int u = tid; u < 224 * 8; u += 256){
    int slot = u >> 3, c8 = u & 7;
    int j = slot < 64 ? slot : wbase + (slot - 64);
    if(j < 0) j = 0;
    short8 vv = *(const short8*)(vb + (size_t)j * 64 + c8 * 8);
    #pragma unroll
    for(int e = 0; e < 8; e++){
      int d = c8 * 8 + e;
      Vt[d * 256 + (((slot >> 3) ^ (d & 7)) << 3) + (slot & 7)] = (unsigned short)vv[e];
    }
  }
  __syncthreads();
  int i0 = qb * 128 + 32 * w;
  const unsigned short* qrow = qg + (size_t)bh * 1024 * 64;
  const unsigned short* krow = kg + (size_t)bh * 1024 * 64;
  short8 qf[2][2];
  #pragma unroll
  for(int m = 0; m < 2; m++)
    #pragma unroll
    for(int s = 0; s < 2; s++)
      qf[m][s] = *(const short8*)(qrow + (size_t)(i0 + m * 16 + (lane & 15)) * 64 + s * 32 + ((lane >> 4) << 3));
  f32x4 sacc[2][8] = {};
  #pragma unroll
  for(int n = 0; n < 8; n++){
    int jk = (n < 4) ? (n * 16 + (lane & 15))
                     : (wbase + 32 * w + (n - 4) * 16 + (lane & 15));
    int jc = jk < 0 ? 0 : jk;
    const unsigned short* kr = krow + (size_t)jc * 64 + ((lane >> 4) << 3);
    short8 k0 = *(const short8*)(kr);
    short8 k1 = *(const short8*)(kr + 32);
    #pragma unroll
    for(int m = 0; m < 2; m++){
      sacc[m][n] = __builtin_amdgcn_mfma_f32_16x16x32_bf16(qf[m][0], k0, sacc[m][n], 0, 0, 0);
      sacc[m][n] = __builtin_amdgcn_mfma_f32_16x16x32_bf16(qf[m][1], k1, sacc[m][n], 0, 0, 0);
    }
  }
  #pragma unroll
  for(int m = 0; m < 2; m++)
    #pragma unroll
    for(int n = 0; n < 8; n++){
      int s_ = n * 16 + (lane & 15);
      int jkey = (n < 4) ? s_ : (wbase + 32 * w + (s_ - 64));
      #pragma unroll
      for(int j = 0; j < 4; j++){
        int qi = i0 + m * 16 + ((lane >> 4) << 2) + j;
        bool ok = (n < 4) ? (jkey <= qi)
                          : (jkey >= 64 && jkey <= qi && (qi - jkey) <= 32);
        sacc[m][n][j] = ok ? sacc[m][n][j] * 0.125f : -1e30f;
      }
    }
  float rsum[2][4];
  #pragma unroll
  for(int m = 0; m < 2; m++)
    #pragma unroll
    for(int j = 0; j < 4; j++){
      float mx = sacc[m][0][j];
      #pragma unroll
      for(int n = 1; n < 8; n++) mx = fmaxf(mx, sacc[m][n][j]);
      mx = fmaxf(mx, __shfl_xor(mx, 1)); mx = fmaxf(mx, __shfl_xor(mx, 2));
      mx = fmaxf(mx, __shfl_xor(mx, 4)); mx = fmaxf(mx, __shfl_xor(mx, 8));
      float sm = 0.f;
      #pragma unroll
      for(int n = 0; n < 8; n++){
        float e = expf(sacc[m][n][j] - mx);
        sacc[m][n][j] = e;
        sm += e;
      }
      sm += __shfl_xor(sm, 1); sm += __shfl_xor(sm, 2);
      sm += __shfl_xor(sm, 4); sm += __shfl_xor(sm, 8);
      rsum[m][j] = sm;
    }
  unsigned short* Pw = Ps[w];
  #pragma unroll
  for(int m = 0; m < 2; m++)
    #pragma unroll
    for(int n = 0; n < 8; n++){
      int s_ = n * 16 + (lane & 15);
      #pragma unroll
      for(int j = 0; j < 4; j++){
        int ql = m * 16 + ((lane >> 4) << 2) + j;
        Pw[ql * 128 + (((s_ >> 3) ^ (ql & 7)) << 3) + (s_ & 7)] = f2bf(sacc[m][n][j]);
      }
    }
  f32x4 oacc[2][4] = {};
  #pragma unroll
  for(int s = 0; s < 4; s++){
    short8 pa[2];
    #pragma unroll
    for(int m = 0; m < 2; m++){
      int ql = m * 16 + (lane & 15);
      int ch = s * 4 + (lane >> 4);
      pa[m] = *(const short8*)(Pw + ql * 128 + ((ch ^ (ql & 7)) << 3));
    }
    int kk = s * 32 + ((lane >> 4) << 3);
    int slot0 = kk < 64 ? kk : 64 + 32 * w + (kk - 64);
    #pragma unroll
    for(int n = 0; n < 4; n++){
      int d = n * 16 + (lane & 15);
      short8 vv = *(const short8*)(Vt + d * 256 + (((slot0 >> 3) ^ (d & 7)) << 3));
      #pragma unroll
      for(int m = 0; m < 2; m++)
        oacc[m][n] = __builtin_amdgcn_mfma_f32_16x16x32_bf16(pa[m], vv, oacc[m][n], 0, 0, 0);
    }
  }
  #pragma unroll
  for(int m = 0; m < 2; m++)
    #pragma unroll
    for(int j = 0; j < 4; j++){
      int ql = m * 16 + ((lane >> 4) << 2) + j;
      float inv = 1.0f / rsum[m][j];
      size_t base = ((size_t)(b * 1024 + i0 + ql)) * 768 + hd * 64;
      #pragma unroll
      for(int n = 0; n < 4; n++){
        int d = n * 16 + (lane & 15);
        h[base + d] += oacc[m][n][j] * inv;
      }
    }
}

// ---------------- loss ----------------
__global__ void k_rowloss(const float* __restrict__ pred, const int* __restrict__ tgt,
                          float* __restrict__ rowloss){
  int row = blockIdx.x * 4 + (threadIdx.x >> 6);
  int lane = threadIdx.x & 63;
  const float* p = pred + (size_t)row * 512 + lane * 8;
  float v[8];
  #pragma unroll
  for(int i = 0; i < 8; i++) v[i] = p[i];
  float mx = v[0];
  #pragma unroll
  for(int i = 1; i < 8; i++) mx = fmaxf(mx, v[i]);
  #pragma unroll
  for(int m = 1; m < 64; m <<= 1) mx = fmaxf(mx, __shfl_xor(mx, m));
  float se = 0.f;
  #pragma unroll
  for(int i = 0; i < 8; i++) se += expf(v[i] - mx);
  #pragma unroll
  for(int m = 1; m < 64; m <<= 1) se += __shfl_xor(se, m);
  int t = tgt[row];
  float pt = 0.f;
  int base = lane * 8;
  #pragma unroll
  for(int i = 0; i < 8; i++) pt = (t == base + i) ? v[i] : pt;
  #pragma unroll
  for(int m = 1; m < 64; m <<= 1) pt += __shfl_xor(pt, m);
  if(lane == 0) rowloss[row] = -(pt - mx - logf(se));
}

__global__ void k_lossfinal(const float* __restrict__ rowloss, float* __restrict__ out){
  int tid = threadIdx.x;
  float s = 0.f;
  for(int i = tid; i < 8192; i += 256) s += rowloss[i];
  #pragma unroll
  for(int m = 32; m >= 1; m >>= 1) s += __shfl_xor(s, m);
  __shared__ float red[4];
  if((tid & 63) == 0) red[tid >> 6] = s;
  __syncthreads();
  if(tid == 0) out[0] = (red[0] + red[1] + red[2] + red[3]) * (1.0f / 8192.0f);
}

extern "C" void kernel_launch(void* const* d_in, const int* in_sizes, int n_in,
                              void* d_out, int out_size, void* d_ws, size_t ws_size,
                              hipStream_t stream){
  const int*   x       = (const int*)d_in[0];
  const int*   targets = (const int*)d_in[1];
  const float* wte     = (const float*)d_in[2];
  const float* pos     = (const float*)d_in[3];
  const float* ln1_g   = (const float*)d_in[4];
  const float* ln1_b   = (const float*)d_in[5];
  const float* wq      = (const float*)d_in[6];
  const float* bq      = (const float*)d_in[7];
  const float* wk      = (const float*)d_in[8];
  const float* bk      = (const float*)d_in[9];
  const float* wv      = (const float*)d_in[10];
  const float* bv      = (const float*)d_in[11];
  const float* ln2_g   = (const float*)d_in[12];
  const float* ln2_b   = (const float*)d_in[13];
  const float* w1      = (const float*)d_in[14];
  const float* b1      = (const float*)d_in[15];
  const float* w2      = (const float*)d_in[16];
  const float* b2      = (const float*)d_in[17];
  const float* lnf_g   = (const float*)d_in[18];
  const float* lnf_b   = (const float*)d_in[19];
  const float* w_out   = (const float*)d_in[20];
  float* out = (float*)d_out;

  char* ws = (char*)d_ws;
  float*          h      = (float*)ws;                              // 25,165,824 B
  unsigned short* a_bf   = (unsigned short*)(ws + 25165824);        // 12,582,912 B
  char*           big    = ws + 37748736;                           // 50,331,648 B (qkv | mlp-mid)
  unsigned short* qbf    = (unsigned short*)big;
  unsigned short* kbf    = (unsigned short*)(big + 12582912);
  unsigned short* vbf    = (unsigned short*)(big + 25165824);
  unsigned short* tbf    = (unsigned short*)big;
  // weights: per-layer slot = 12,976,128 B (wqkv_t 3.54MB | w1_t 4.72MB | w2_t 4.72MB)
  bool mega = ws_size >= 192782336ull;              // all-8-layer conversion fits?
  unsigned short* wall   = (unsigned short*)(ws + 88080384);
  size_t wend = 88080384ull + (mega ? 103809024ull : 12976128ull);
  unsigned short* wout_t = (unsigned short*)(ws + wend);            // 786,432 B
  float*          qkvb   = (float*)(ws + wend + 786432);            // 9,216 or 73,728 B
  float*          rowls  = (float*)(ws + wend + 786432 + (mega ? 73728 : 9216));

  if(mega){
    k_convert_all<<<dim3(793, 4), 256, 0, stream>>>(wq, wk, wv, w1, w2, bq, bk, bv,
                                                    wall, qkvb, 0, 0);
    k_convert_all<<<dim3(793, 4), 256, 0, stream>>>(wq, wk, wv, w1, w2, bq, bk, bv,
                                                    wall, qkvb, 4, 4);
  }
  k_transpose<<<48, 256, 0, stream>>>(w_out, wout_t, 768, 512);     // 3 ty x 16 tx
  k_embed<<<6144, 256, 0, stream>>>(x, wte, pos, h);
  for(int l = 0; l < 8; l++){
    if(!mega)
      k_convert_all<<<dim3(793, 1), 256, 0, stream>>>(wq, wk, wv, w1, w2, bq, bk, bv,
                                                      wall, qkvb, l, 0);
    int slot = mega ? l : 0;
    unsigned short* wqkv_l = wall + (size_t)slot * 6488064;
    unsigned short* w1_l   = wqkv_l + 1769472;
    unsigned short* w2_l   = w1_l + 2359296;
    float*          qkvb_l = qkvb + slot * 2304;
    k_ln<<<2048, 256, 0, stream>>>(h, ln1_g + l * 768, ln1_b + l * 768, a_bf);
    k_gemm<0,4,4><<<dim3(18, 32), 512, 0, stream>>>(a_bf, wqkv_l, qkvb_l, 768, nullptr, qbf, kbf, vbf);
    k_attn<<<dim3(8, 96), 256, 0, stream>>>(qbf, kbf, vbf, h);
    k_ln<<<2048, 256, 0, stream>>>(h, ln2_g + l * 768, ln2_b + l * 768, a_bf);
    k_gemm<1,4,4><<<dim3(24, 32), 512, 0, stream>>>(a_bf, w1_l, b1 + l * 3072, 768, nullptr, tbf, nullptr, nullptr);
    k_gemm<2,2,2><<<dim3(12, 64), 256, 0, stream>>>(tbf, w2_l, b2 + l * 768, 3072, h, nullptr, nullptr, nullptr);
  }
  k_ln<<<2048, 256, 0, stream>>>(h, lnf_g, lnf_b, a_bf);
  k_gemm<3,2,2><<<dim3(8, 64), 256, 0, stream>>>(a_bf, wout_t, nullptr, 768, out, nullptr, nullptr, nullptr);
  k_rowloss<<<2048, 256, 0, stream>>>(out, targets, rowls);
  k_lossfinal<<<1, 256, 0, stream>>>(rowls, out + 4194304);
}